// Round 15
// baseline (7273.853 us; speedup 1.0000x reference)
//
#include <hip/hip_runtime.h>

// ---------------------------------------------------------------------------
// SelfAttention (QKV -> softmax(QK^T/sqrt(D)) V) -> LSTM(1024 steps)
// B=16, S=1024, D=H=2048.  All heavy math in bf16 MFMA, fp32 accumulate.
// ---------------------------------------------------------------------------

typedef unsigned short u16;
typedef unsigned int u32;
typedef unsigned long long u64;
typedef __attribute__((ext_vector_type(8))) __bf16 bf16x8;
typedef __attribute__((ext_vector_type(8))) unsigned short u16x8;
typedef __attribute__((ext_vector_type(4))) float f32x4;
typedef __attribute__((ext_vector_type(4))) unsigned int u32x4;

#define DEV static __device__ __forceinline__

DEV u16 f2bf(float f) {  // RTNE float->bf16 (finite inputs)
  union { float f; unsigned u; } x; x.f = f;
  return (u16)((x.u + 0x7FFFu + ((x.u >> 16) & 1u)) >> 16);
}
DEV float bf2f(u16 h) {
  union { unsigned u; float f; } x; x.u = (unsigned)h << 16;
  return x.f;
}
DEV void gload_lds16(const void* g, void* l) {
  __builtin_amdgcn_global_load_lds(
      (const __attribute__((address_space(1))) unsigned int*)g,
      (__attribute__((address_space(3))) unsigned int*)l, 16, 0, 0);
}

// -------------------------- fp32 -> bf16 convert ---------------------------
__global__ __launch_bounds__(256) void k_cvt(const float* __restrict__ in,
                                             u16* __restrict__ out, long n) {
  long i = (((long)blockIdx.x << 8) | threadIdx.x) << 3;
  if (i >= n) return;
  float4 f0 = *(const float4*)(in + i);
  float4 f1 = *(const float4*)(in + i + 4);
  u16x8 p;
  p[0] = f2bf(f0.x); p[1] = f2bf(f0.y); p[2] = f2bf(f0.z); p[3] = f2bf(f0.w);
  p[4] = f2bf(f1.x); p[5] = f2bf(f1.y); p[6] = f2bf(f1.z); p[7] = f2bf(f1.w);
  *(u16x8*)(out + i) = p;
}

__global__ __launch_bounds__(256) void k_addb(const float* __restrict__ a,
                                              const float* __restrict__ b,
                                              float* __restrict__ o, int n) {
  int i = blockIdx.x * 256 + threadIdx.x;
  if (i < n) o[i] = a[i] + b[i];
}

// ----------------------- 256² deep-pipelined NT GEMM -----------------------
// C[m,n] = scale*sum_k A[m,k]B[n,k] + bias[n].  BM=BN=256, BK=32, 512 thr
// (8 waves 2Mx4N, 128x64/wave).  LDS 4 slots x 32KB, st_16x32 XOR swizzle.
// R15: fragment double-buffering — ds_reads of tile kt+1 issued alongside
// the MFMAs of tile kt (separate reg sets), ONE barrier per K-step, MFMA
// never waits on LDS.  vmcnt(8) steady state (2 tiles in flight after the
// needed one retires); tail 8/4/0.  Slot kt&3 is restaged 4 steps later,
// >=2 barriers after every wave's lgkmcnt(0)-drained reads of it.
template<int OBF>
__global__ __launch_bounds__(512, 2) void k_gemm256(
    const u16* __restrict__ A, const u16* __restrict__ B, void* __restrict__ Cv,
    const float* __restrict__ bias, float scale, int N, int K,
    long sA, long sB, long sC) {
  extern __shared__ u16 lds[];
  u16* As = lds;                    // [4][8192]
  u16* Bs = lds + 32768;            // [4][8192]
  const int tid = threadIdx.x;
  const int lane = tid & 63, wid = tid >> 6;
  const int wm = (wid >> 2) & 1, wn = wid & 3;
  const int gx = gridDim.x;
  int lin = blockIdx.y * gx + blockIdx.x;
  const int nwg = gx * gridDim.y;
  if ((nwg & 7) == 0) lin = (lin & 7) * (nwg >> 3) + (lin >> 3);
  const long bm = (long)(lin / gx) << 8;
  const long bn = (long)(lin % gx) << 8;
  A += (long)blockIdx.z * sA;
  B += (long)blockIdx.z * sB;
  const int NK = K >> 5;            // >= 6 and even for all our shapes

  u32 srow[2], scolb[2];
#pragma unroll
  for (int p = 0; p < 2; ++p) {
    const u32 q = (u32)(p * 8192 + tid * 16);
    const u32 qp = q ^ (((q >> 9) & 1u) << 5);
    srow[p] = qp >> 6; scolb[p] = qp & 63u;
  }
#define STAGE256(S, KT)                                                      \
  {                                                                          \
    _Pragma("unroll")                                                        \
    for (int p = 0; p < 2; ++p) {                                            \
      const u32 q = (u32)(p * 8192 + tid * 16);                              \
      gload_lds16(A + (bm + srow[p]) * (long)K + (KT) * 32 + (scolb[p] >> 1),\
                  (char*)As + (S) * 16384 + q);                              \
      gload_lds16(B + (bn + srow[p]) * (long)K + (KT) * 32 + (scolb[p] >> 1),\
                  (char*)Bs + (S) * 16384 + q);                              \
    }                                                                        \
  }

  const int fr = lane & 15, fkb = ((lane >> 4) << 3) << 1;
  u32 abyte[8], bbyte[4];
#pragma unroll
  for (int mi = 0; mi < 8; ++mi) {
    const u32 row = (u32)(wm * 128 + mi * 16 + fr);
    abyte[mi] = (row * 64 + (u32)fkb) ^ ((row & 8u) ? 32u : 0u);
  }
#pragma unroll
  for (int ni = 0; ni < 4; ++ni) {
    const u32 row = (u32)(wn * 64 + ni * 16 + fr);
    bbyte[ni] = (row * 64 + (u32)fkb) ^ ((row & 8u) ? 32u : 0u);
  }

  f32x4 acc[8][4] = {};
  bf16x8 avA[8], bvA[4], avB[8], bvB[4];
#define READF(AV, BV, SLOT)                                                  \
  {                                                                          \
    const char* sa = (const char*)As + (SLOT) * 16384;                       \
    const char* sb = (const char*)Bs + (SLOT) * 16384;                       \
    _Pragma("unroll")                                                        \
    for (int mi = 0; mi < 8; ++mi) AV[mi] = *(const bf16x8*)(sa + abyte[mi]);\
    _Pragma("unroll")                                                        \
    for (int ni = 0; ni < 4; ++ni) BV[ni] = *(const bf16x8*)(sb + bbyte[ni]);\
  }
#define MFMAS(AV, BV)                                                        \
  {                                                                          \
    __builtin_amdgcn_s_setprio(1);                                           \
    _Pragma("unroll")                                                        \
    for (int mi = 0; mi < 8; ++mi)                                           \
      _Pragma("unroll")                                                      \
      for (int ni = 0; ni < 4; ++ni)                                         \
        acc[mi][ni] = __builtin_amdgcn_mfma_f32_16x16x32_bf16(               \
            AV[mi], BV[ni], acc[mi][ni], 0, 0, 0);                           \
    __builtin_amdgcn_s_setprio(0);                                           \
  }
#define VMC(N) asm volatile("s_waitcnt vmcnt(" #N ")" ::: "memory");
#define LGK0   asm volatile("s_waitcnt lgkmcnt(0)" ::: "memory");

  // prologue: 3 tiles in flight; read tile 0 fragments
  STAGE256(0, 0)
  STAGE256(1, 1)
  STAGE256(2, 2)
  VMC(8)
  __builtin_amdgcn_s_barrier();
  READF(avA, bvA, 0)
  LGK0

  int kt = 0;
  for (; kt < NK - 4; kt += 2) {
    STAGE256((kt + 3) & 3, kt + 3)
    VMC(8)
    __builtin_amdgcn_s_barrier();
    READF(avB, bvB, (kt + 1) & 3)
    MFMAS(avA, bvA)
    LGK0
    STAGE256((kt + 4) & 3, kt + 4)
    VMC(8)
    __builtin_amdgcn_s_barrier();
    READF(avA, bvA, (kt + 2) & 3)
    MFMAS(avB, bvB)
    LGK0
  }
  // kt == NK-4 here; staged through NK-2; avA holds tile NK-4
  STAGE256((NK - 1) & 3, NK - 1)
  VMC(8)
  __builtin_amdgcn_s_barrier();
  READF(avB, bvB, (NK - 3) & 3)
  MFMAS(avA, bvA)            // tile NK-4
  LGK0
  VMC(4)
  __builtin_amdgcn_s_barrier();
  READF(avA, bvA, (NK - 2) & 3)
  MFMAS(avB, bvB)            // tile NK-3
  LGK0
  VMC(0)
  __builtin_amdgcn_s_barrier();
  READF(avB, bvB, (NK - 1) & 3)
  MFMAS(avA, bvA)            // tile NK-2
  LGK0
  MFMAS(avB, bvB)            // tile NK-1
#undef STAGE256
#undef READF
#undef MFMAS
#undef VMC
#undef LGK0

  // epilogue: scale + bias + store (bf16 or fp32)
  const long cb = (long)blockIdx.z * sC;
#pragma unroll
  for (int ni = 0; ni < 4; ++ni) {
    const long col = bn + wn * 64 + ni * 16 + fr;
    const float bb = bias ? bias[col] : 0.f;
#pragma unroll
    for (int mi = 0; mi < 8; ++mi) {
      const long r0 = bm + wm * 128 + mi * 16 + ((lane >> 4) << 2);
#pragma unroll
      for (int r = 0; r < 4; ++r) {
        const float v = acc[mi][ni][r] * scale + bb;
        const long off = cb + (r0 + r) * (long)N + col;
        if (OBF) ((u16*)Cv)[off] = f2bf(v);
        else     ((float*)Cv)[off] = v;
      }
    }
  }
}

// ------------------------------ row softmax --------------------------------
__global__ __launch_bounds__(256) void k_softmax(const float* __restrict__ S,
                                                 u16* __restrict__ P) {
  __shared__ float red[8];
  const long row = blockIdx.x;
  const float* sr = S + (row << 10);
  const int t = threadIdx.x, lane = t & 63, w = t >> 6;
  float v0 = sr[t], v1 = sr[t + 256], v2 = sr[t + 512], v3 = sr[t + 768];
  float m = fmaxf(fmaxf(v0, v1), fmaxf(v2, v3));
#pragma unroll
  for (int o = 32; o; o >>= 1) m = fmaxf(m, __shfl_xor(m, o));
  if (lane == 0) red[w] = m;
  __syncthreads();
  m = fmaxf(fmaxf(red[0], red[1]), fmaxf(red[2], red[3]));
  v0 = __expf(v0 - m); v1 = __expf(v1 - m); v2 = __expf(v2 - m); v3 = __expf(v3 - m);
  float s = v0 + v1 + v2 + v3;
#pragma unroll
  for (int o = 32; o; o >>= 1) s += __shfl_xor(s, o);
  if (lane == 0) red[4 + w] = s;
  __syncthreads();
  s = red[4] + red[5] + red[6] + red[7];
  const float rs = 1.f / s;
  u16* pr = P + (row << 10);
  pr[t] = f2bf(v0 * rs); pr[t + 256] = f2bf(v1 * rs);
  pr[t + 512] = f2bf(v2 * rs); pr[t + 768] = f2bf(v3 * rs);
}

// ------------------------- V transpose (per batch) -------------------------
__global__ __launch_bounds__(256) void k_transpose(const u16* __restrict__ V,
                                                   u16* __restrict__ VT) {
  __shared__ __attribute__((aligned(16))) u16 tile[64][80];
  const long b = blockIdx.z;
  const long t0 = (long)blockIdx.y << 6, d0 = (long)blockIdx.x << 6;
  const int r = threadIdx.x >> 3, c8 = (threadIdx.x & 7) << 3;
  const u16* src = V + ((b << 10) + t0) * 2048 + d0;
#pragma unroll
  for (int p = 0; p < 2; ++p) {
    const int rr = r + p * 32;
    *(u16x8*)&tile[rr][c8] = *(const u16x8*)(src + (long)rr * 2048 + c8);
  }
  __syncthreads();
  u16* dst = VT + ((b << 11) + d0) * 1024 + t0;
#pragma unroll
  for (int p = 0; p < 2; ++p) {
    const int dr = r + p * 32;
    u16x8 pk;
#pragma unroll
    for (int q = 0; q < 8; ++q) pk[q] = tile[c8 + q][dr];
    *(u16x8*)(dst + (long)dr * 1024 + c8) = pk;
  }
}

// ------------------------------ LSTM recurrence ----------------------------
// ROUND-9 VERBATIM (best measured: ~5.1-5.2 ms).  128 blocks x 256 threads.
DEV bf16x8 wread(const char* wlds, int nrow, int k) {
  int byte = (nrow << 12) + (k << 1);
  byte ^= (nrow & 7) << 4;
  return *(const bf16x8*)(wlds + byte);
}
DEV float sigm(float x) { return 1.f / (1.f + __expf(-x)); }
DEV float tanh_fast(float x) { return 1.f - 2.f / (1.f + __expf(2.f * x)); }

__global__ __launch_bounds__(256, 1) void k_lstm(
    const u16* __restrict__ xg, const u16* __restrict__ whh,
    u16* __restrict__ hbuf, float* __restrict__ out,
    unsigned* __restrict__ flg) {
  extern __shared__ char smem[];
  char* wlds = smem;                       // 32 x 2048 bf16 = 131072 B (gates 0,1)
  float* red = (float*)(smem + 131072);    // [4 waves][16 batch x 64 gcol] = 16 KB
  const int tid = threadIdx.x, lane = tid & 63, wave = tid >> 6;
  const int j0 = blockIdx.x << 4;          // 16 columns per block
  const int am = lane & 15, ak = (lane >> 4) << 3;
  const int bb = tid >> 4, jj = tid & 15;  // gate-stage cell (all 256 threads)

  for (int it = 0; it < 32; ++it) {
    const long grow = ((long)(it >> 4) << 11) + j0 + (it & 15);
    const u16* src = whh + grow * 2048 + (tid << 3);
    int byte = (it << 12) + (tid << 4);
    byte ^= (it & 7) << 4;
    *(bf16x8*)(wlds + byte) = *(const bf16x8*)src;
  }
  bf16x8 wf[2][16];
#pragma unroll
  for (int g2 = 0; g2 < 2; ++g2)
#pragma unroll
    for (int ks = 0; ks < 16; ++ks)
      wf[g2][ks] = *(const bf16x8*)(whh + ((long)((2 + g2) << 11) + j0 + am) * 2048 +
                                    (wave << 9) + (ks << 5) + ak);
  __syncthreads();

  float c = 0.f;
  unsigned* const myflag = flg + (((wave << 5) + (lane & 31)) << 2);  // 16B stride
  u16 xv[4];
#pragma unroll
  for (int g = 0; g < 4; ++g)
    xv[g] = xg[((long)bb << 10) * 8192 + (g << 11) + j0 + jj];

  for (int t = 0; t < 1024; ++t) {
    const int par = t & 1;
    unsigned dep = 0;
    if (t) {
      const unsigned tgt = (unsigned)t;
      unsigned v = tgt;
      for (;;) {
        if (lane < 32)
          v = __hip_atomic_load(myflag, __ATOMIC_RELAXED, __HIP_MEMORY_SCOPE_AGENT);
        if (__all(v >= tgt)) break;
        __builtin_amdgcn_s_sleep(1);
      }
      dep = v >> 20;
    }
    asm volatile("" : "+v"(dep)::);

    const u16* hbase = hbuf + ((par ^ 1) << 15);
    const u32 voff = ((am << 11) + (wave << 9) + ak + dep) << 1;
    u32x4 hd[16];
#define HLD(I, OFF)                                                          \
    asm volatile("global_load_dwordx4 %0, %1, %2 offset:" #OFF " sc0 sc1"    \
                 : "=v"(hd[I]) : "v"(voff), "s"(hbase));
    HLD(0, 0)    HLD(1, 64)   HLD(2, 128)  HLD(3, 192)
    HLD(4, 256)  HLD(5, 320)  HLD(6, 384)  HLD(7, 448)
    HLD(8, 512)  HLD(9, 576)  HLD(10, 640) HLD(11, 704)
    HLD(12, 768) HLD(13, 832) HLD(14, 896) HLD(15, 960)
#undef HLD
    asm volatile("s_waitcnt vmcnt(0)" ::: "memory");
    __builtin_amdgcn_sched_barrier(0);

    f32x4 a0 = {0.f, 0.f, 0.f, 0.f}, a1 = a0, a2 = a0, a3 = a0;
#pragma unroll
    for (int ks = 0; ks < 16; ++ks) {
      union { u32x4 d; bf16x8 v; } u;
      u.d = hd[ks];
      const int k = (wave << 9) + (ks << 5) + ak;
      a0 = __builtin_amdgcn_mfma_f32_16x16x32_bf16(u.v, wread(wlds, am, k),      a0, 0, 0, 0);
      a1 = __builtin_amdgcn_mfma_f32_16x16x32_bf16(u.v, wread(wlds, am + 16, k), a1, 0, 0, 0);
      a2 = __builtin_amdgcn_mfma_f32_16x16x32_bf16(u.v, wf[0][ks], a2, 0, 0, 0);
      a3 = __builtin_amdgcn_mfma_f32_16x16x32_bf16(u.v, wf[1][ks], a3, 0, 0, 0);
    }
    {
      float* rw = red + (wave << 10);
      const int mrow = (lane >> 4) << 2;
#pragma unroll
      for (int r = 0; r < 4; ++r) {
        rw[(mrow + r) * 64 + am]      = a0[r];
        rw[(mrow + r) * 64 + 16 + am] = a1[r];
        rw[(mrow + r) * 64 + 32 + am] = a2[r];
        rw[(mrow + r) * 64 + 48 + am] = a3[r];
      }
    }
    __syncthreads();
    float g4[4];
#pragma unroll
    for (int g = 0; g < 4; ++g) {
      const int n = (bb << 6) + (g << 4) + jj;
      g4[g] = red[n] + red[1024 + n] + red[2048 + n] + red[3072 + n] + bf2f(xv[g]);
    }
    const float gi = sigm(g4[0]);
    const float gf = sigm(g4[1]);
    const float gg = tanh_fast(g4[2]);
    const float go = sigm(g4[3]);
    c = gf * c + gi * gg;
    const float h = go * tanh_fast(c);
    {
      const unsigned hb = (unsigned)f2bf(h);
      const unsigned p1 = (unsigned)__shfl_xor((int)hb, 1);
      const unsigned w2 = (hb & 0xFFFFu) | (p1 << 16);
      const unsigned p2 = (unsigned)__shfl_xor((int)w2, 2);
      if ((jj & 3) == 0) {
        const u64 hw = (u64)w2 | ((u64)p2 << 32);
        u16* dst = hbuf + (par << 15) + (bb << 11) + j0 + jj;
        __hip_atomic_store((u64*)dst, hw, __ATOMIC_RELAXED, __HIP_MEMORY_SCOPE_AGENT);
      }
    }
    asm volatile("s_waitcnt vmcnt(0)" ::: "memory");
    __syncthreads();
    if (tid == 0)
      __hip_atomic_store(flg + (blockIdx.x << 2), (unsigned)(t + 1),
                         __ATOMIC_RELAXED, __HIP_MEMORY_SCOPE_AGENT);
    out[(((long)(bb << 10) + t) << 11) + j0 + jj] = h;
    {
      const int tn = (t + 1 < 1024) ? t + 1 : 0;
#pragma unroll
      for (int g = 0; g < 4; ++g)
        xv[g] = xg[((long)((bb << 10) + tn)) * 8192 + (g << 11) + j0 + jj];
    }
    asm volatile("" ::: "memory");
  }
}

// ------------------------------- launcher ----------------------------------
extern "C" void kernel_launch(void* const* d_in, const int* in_sizes, int n_in,
                              void* d_out, int out_size, void* d_ws, size_t ws_size,
                              hipStream_t stream) {
  const float* feats = (const float*)d_in[0];
  const float* Wq = (const float*)d_in[1];
  const float* bq = (const float*)d_in[2];
  const float* Wk = (const float*)d_in[3];
  const float* bk = (const float*)d_in[4];
  const float* Wv = (const float*)d_in[5];
  const float* bv = (const float*)d_in[6];
  const float* Wih = (const float*)d_in[7];
  const float* Whh = (const float*)d_in[8];
  const float* bih = (const float*)d_in[9];
  const float* bhh = (const float*)d_in[10];
  float* out = (float*)d_out;
  char* ws = (char*)d_ws;

  u16* feats16 = (u16*)(ws + 0L);
  u16* q16     = (u16*)(ws + 67108864L);
  u16* k16     = (u16*)(ws + 134217728L);
  u16* v16     = (u16*)(ws + 201326592L);
  u16* vT16    = feats16;                   // reuse after QKV
  u16* P16     = q16;                       // reuse after scores GEMM
  u16* xg16    = (u16*)(ws + 0L);           // reuse [0,256MB) after PV
  u16* nf16    = (u16*)(ws + 268435456L);
  u16* wq16    = (u16*)(ws + 335544320L);
  u16* wk16    = (u16*)(ws + 343932928L);
  u16* wv16    = (u16*)(ws + 352321536L);
  u16* wih16   = (u16*)(ws + 360710144L);
  u16* whh16   = (u16*)(ws + 394264576L);
  float* biassum = (float*)(ws + 427819008L);
  u16* hbuf    = (u16*)(ws + 427851776L);   // [2][16][2048] bf16
  unsigned* flg = (unsigned*)(ws + 427982848L);  // 128 x 16B flag slots
  float* scoresf = (float*)d_out;           // d_out as scratch; LSTM overwrites

  k_cvt<<<16384, 256, 0, stream>>>(feats, feats16, 33554432L);
  k_cvt<<<2048, 256, 0, stream>>>(Wq, wq16, 4194304L);
  k_cvt<<<2048, 256, 0, stream>>>(Wk, wk16, 4194304L);
  k_cvt<<<2048, 256, 0, stream>>>(Wv, wv16, 4194304L);
  k_cvt<<<8192, 256, 0, stream>>>(Wih, wih16, 16777216L);
  k_cvt<<<8192, 256, 0, stream>>>(Whh, whh16, 16777216L);
  k_addb<<<32, 256, 0, stream>>>(bih, bhh, biassum, 8192);

  (void)hipFuncSetAttribute((const void*)k_gemm256<1>, hipFuncAttributeMaxDynamicSharedMemorySize, 131072);
  (void)hipFuncSetAttribute((const void*)k_gemm256<0>, hipFuncAttributeMaxDynamicSharedMemorySize, 131072);
  // q,k,v = feats @ W^T + b   (256² deep-pipelined kernel, 128KB dyn LDS)
  k_gemm256<1><<<dim3(8, 64, 1), 512, 131072, stream>>>(feats16, wq16, q16, bq, 1.f, 2048, 2048, 0, 0, 0);
  k_gemm256<1><<<dim3(8, 64, 1), 512, 131072, stream>>>(feats16, wk16, k16, bk, 1.f, 2048, 2048, 0, 0, 0);
  k_gemm256<1><<<dim3(8, 64, 1), 512, 131072, stream>>>(feats16, wv16, v16, bv, 1.f, 2048, 2048, 0, 0, 0);
  // scores = q k^T / sqrt(2048)   (batched 256², fp32 into d_out scratch)
  k_gemm256<0><<<dim3(4, 4, 16), 512, 131072, stream>>>(q16, k16, scoresf, nullptr,
                                                        0.022097086912079608f, 1024, 2048,
                                                        2097152, 2097152, 1048576);
  k_softmax<<<16384, 256, 0, stream>>>(scoresf, P16);
  k_transpose<<<dim3(32, 16, 16), 256, 0, stream>>>(v16, vT16);
  // new_feats = P @ V  (via V^T, batched 256²)
  k_gemm256<1><<<dim3(8, 4, 16), 512, 131072, stream>>>(P16, vT16, nf16, nullptr, 1.f,
                                                        2048, 1024,
                                                        1048576, 2097152, 2097152);
  // xg = new_feats @ W_ih^T + (b_ih + b_hh)   (256² kernel)
  k_gemm256<1><<<dim3(32, 64, 1), 512, 131072, stream>>>(nf16, wih16, xg16, biassum, 1.f, 8192, 2048, 0, 0, 0);

  // LSTM recurrence (persistent kernel, R9 per-wave flag sync)
  hipMemsetAsync(ws + 427851776L, 0, 131072 + 4096, stream);  // hbuf + flags
  const int dynlds = 131072 + 16384;  // W gates 0,1 + red
  (void)hipFuncSetAttribute((const void*)k_lstm, hipFuncAttributeMaxDynamicSharedMemorySize, dynlds);
  void* kargs[] = {(void*)&xg16, (void*)&whh16, (void*)&hbuf, (void*)&out, (void*)&flg};
  hipError_t ce = hipLaunchCooperativeKernel((const void*)k_lstm, dim3(128), dim3(256),
                                             kargs, dynlds, stream);
  if (ce != hipSuccess) {
    k_lstm<<<dim3(128), dim3(256), dynlds, stream>>>(xg16, whh16, hbuf, out, flg);
  }
}

// Round 16
// 6671.460 us; speedup vs baseline: 1.0903x; 1.0903x over previous
//
#include <hip/hip_runtime.h>

// ---------------------------------------------------------------------------
// SelfAttention (QKV -> softmax(QK^T/sqrt(D)) V) -> LSTM(1024 steps)
// B=16, S=1024, D=H=2048.  All heavy math in bf16 MFMA, fp32 accumulate.
// ---------------------------------------------------------------------------

typedef unsigned short u16;
typedef unsigned int u32;
typedef unsigned long long u64;
typedef __attribute__((ext_vector_type(8))) __bf16 bf16x8;
typedef __attribute__((ext_vector_type(8))) unsigned short u16x8;
typedef __attribute__((ext_vector_type(4))) float f32x4;
typedef __attribute__((ext_vector_type(4))) unsigned int u32x4;

#define DEV static __device__ __forceinline__

DEV u16 f2bf(float f) {  // RTNE float->bf16 (finite inputs)
  union { float f; unsigned u; } x; x.f = f;
  return (u16)((x.u + 0x7FFFu + ((x.u >> 16) & 1u)) >> 16);
}
DEV float bf2f(u16 h) {
  union { unsigned u; float f; } x; x.u = (unsigned)h << 16;
  return x.f;
}
DEV void gload_lds16(const void* g, void* l) {
  __builtin_amdgcn_global_load_lds(
      (const __attribute__((address_space(1))) unsigned int*)g,
      (__attribute__((address_space(3))) unsigned int*)l, 16, 0, 0);
}

// ---------------- fused fp32 -> bf16 convert (6 tensors, 1 dispatch) -------
DEV void cvt8(const float* in, u16* out, long i) {
  float4 f0 = *(const float4*)(in + i);
  float4 f1 = *(const float4*)(in + i + 4);
  u16x8 p;
  p[0] = f2bf(f0.x); p[1] = f2bf(f0.y); p[2] = f2bf(f0.z); p[3] = f2bf(f0.w);
  p[4] = f2bf(f1.x); p[5] = f2bf(f1.y); p[6] = f2bf(f1.z); p[7] = f2bf(f1.w);
  *(u16x8*)(out + i) = p;
}
// block ranges (2048 elems/block): [0,16384) feats | [16384,18432) wq |
// [18432,20480) wk | [20480,22528) wv | [22528,30720) wih | [30720,38912) whh
__global__ __launch_bounds__(256) void k_cvt6(
    const float* __restrict__ f,  u16* __restrict__ of,
    const float* __restrict__ w0, u16* __restrict__ o0,
    const float* __restrict__ w1, u16* __restrict__ o1,
    const float* __restrict__ w2, u16* __restrict__ o2,
    const float* __restrict__ w3, u16* __restrict__ o3,
    const float* __restrict__ w4, u16* __restrict__ o4) {
  const int b = blockIdx.x;
  const float* src; u16* dst; long base;
  if (b < 16384)      { src = f;  dst = of; base = (long)b << 11; }
  else if (b < 18432) { src = w0; dst = o0; base = (long)(b - 16384) << 11; }
  else if (b < 20480) { src = w1; dst = o1; base = (long)(b - 18432) << 11; }
  else if (b < 22528) { src = w2; dst = o2; base = (long)(b - 20480) << 11; }
  else if (b < 30720) { src = w3; dst = o3; base = (long)(b - 22528) << 11; }
  else                { src = w4; dst = o4; base = (long)(b - 30720) << 11; }
  cvt8(src, dst, base + ((long)threadIdx.x << 3));
}

// bias prep: biasqkv[3][2048] = {bq,bk,bv};  biassum[8192] = bih + bhh
__global__ __launch_bounds__(256) void k_biasprep(
    const float* __restrict__ bq, const float* __restrict__ bk,
    const float* __restrict__ bv, const float* __restrict__ bih,
    const float* __restrict__ bhh, float* __restrict__ biasqkv,
    float* __restrict__ biassum) {
  const int i = blockIdx.x * 256 + threadIdx.x;
  if (i < 2048)       biasqkv[i] = bq[i];
  else if (i < 4096)  biasqkv[i] = bk[i - 2048];
  else if (i < 6144)  biasqkv[i] = bv[i - 4096];
  else                { const int j = i - 6144; biassum[j] = bih[j] + bhh[j]; }
}

// ----------------------- 256² deep-pipelined NT GEMM -----------------------
// C[m,n] = scale*sum_k A[m,k]B[n,k] + bias[n].  BM=BN=256, BK=32, 512 thr
// (8 waves 2Mx4N, 128x64/wave).  LDS 4 slots x 32KB, st_16x32 XOR swizzle
// (both-sides: inverse-swizzled global SOURCE for linear global_load_lds
// dest + swizzled ds_read).  3-tile-deep prefetch, vmcnt(12) steady state
// (never 0 in main loop; tail 8/4/0).  Batched via blockIdx.z strides.
// [R14-proven schedule; R15's frag double-buffer regressed via reg pressure]
template<int OBF>
__global__ __launch_bounds__(512, 2) void k_gemm256(
    const u16* __restrict__ A, const u16* __restrict__ B, void* __restrict__ Cv,
    const float* __restrict__ bias, float scale, int N, int K,
    long sA, long sB, long sC, long sBias) {
  extern __shared__ u16 lds[];
  u16* As = lds;                    // [4][8192]
  u16* Bs = lds + 32768;            // [4][8192]
  const int tid = threadIdx.x;
  const int lane = tid & 63, wid = tid >> 6;
  const int wm = (wid >> 2) & 1, wn = wid & 3;
  const int gx = gridDim.x;
  int lin = blockIdx.y * gx + blockIdx.x;
  const int nwg = gx * gridDim.y;
  if ((nwg & 7) == 0) lin = (lin & 7) * (nwg >> 3) + (lin >> 3);
  const long bm = (long)(lin / gx) << 8;
  const long bn = (long)(lin % gx) << 8;
  A += (long)blockIdx.z * sA;
  B += (long)blockIdx.z * sB;
  if (bias) bias += (long)blockIdx.z * sBias;
  const int NK = K >> 5;

  u32 srow[2], scolb[2];
#pragma unroll
  for (int p = 0; p < 2; ++p) {
    const u32 q = (u32)(p * 8192 + tid * 16);
    const u32 qp = q ^ (((q >> 9) & 1u) << 5);
    srow[p] = qp >> 6; scolb[p] = qp & 63u;
  }
#define STAGE256(S, KT)                                                      \
  {                                                                          \
    _Pragma("unroll")                                                        \
    for (int p = 0; p < 2; ++p) {                                            \
      const u32 q = (u32)(p * 8192 + tid * 16);                              \
      gload_lds16(A + (bm + srow[p]) * (long)K + (KT) * 32 + (scolb[p] >> 1),\
                  (char*)As + (S) * 16384 + q);                              \
      gload_lds16(B + (bn + srow[p]) * (long)K + (KT) * 32 + (scolb[p] >> 1),\
                  (char*)Bs + (S) * 16384 + q);                              \
    }                                                                        \
  }

  const int fr = lane & 15, fkb = ((lane >> 4) << 3) << 1;
  u32 abyte[8], bbyte[4];
#pragma unroll
  for (int mi = 0; mi < 8; ++mi) {
    const u32 row = (u32)(wm * 128 + mi * 16 + fr);
    abyte[mi] = (row * 64 + (u32)fkb) ^ ((row & 8u) ? 32u : 0u);
  }
#pragma unroll
  for (int ni = 0; ni < 4; ++ni) {
    const u32 row = (u32)(wn * 64 + ni * 16 + fr);
    bbyte[ni] = (row * 64 + (u32)fkb) ^ ((row & 8u) ? 32u : 0u);
  }

  f32x4 acc[8][4] = {};
#define COMPUTE256(SLOT)                                                     \
  {                                                                          \
    const char* sa = (const char*)As + (SLOT) * 16384;                       \
    const char* sb = (const char*)Bs + (SLOT) * 16384;                       \
    bf16x8 av[8], bv[4];                                                     \
    _Pragma("unroll")                                                        \
    for (int mi = 0; mi < 8; ++mi) av[mi] = *(const bf16x8*)(sa + abyte[mi]);\
    _Pragma("unroll")                                                        \
    for (int ni = 0; ni < 4; ++ni) bv[ni] = *(const bf16x8*)(sb + bbyte[ni]);\
    asm volatile("s_waitcnt lgkmcnt(0)" ::: "memory");                       \
    __builtin_amdgcn_s_barrier();                                            \
    __builtin_amdgcn_s_setprio(1);                                           \
    _Pragma("unroll")                                                        \
    for (int mi = 0; mi < 8; ++mi)                                           \
      _Pragma("unroll")                                                      \
      for (int ni = 0; ni < 4; ++ni)                                         \
        acc[mi][ni] = __builtin_amdgcn_mfma_f32_16x16x32_bf16(               \
            av[mi], bv[ni], acc[mi][ni], 0, 0, 0);                           \
    __builtin_amdgcn_s_setprio(0);                                           \
  }

  STAGE256(0, 0)
  STAGE256(1, 1)
  STAGE256(2, 2)
  int kt = 0;
  for (; kt < NK - 3; ++kt) {
    STAGE256((kt + 3) & 3, kt + 3)
    asm volatile("s_waitcnt vmcnt(12)" ::: "memory");
    __builtin_amdgcn_s_barrier();
    COMPUTE256(kt & 3)
  }
  asm volatile("s_waitcnt vmcnt(8)" ::: "memory");
  __builtin_amdgcn_s_barrier();
  COMPUTE256(kt & 3) ++kt;
  asm volatile("s_waitcnt vmcnt(4)" ::: "memory");
  __builtin_amdgcn_s_barrier();
  COMPUTE256(kt & 3) ++kt;
  asm volatile("s_waitcnt vmcnt(0)" ::: "memory");
  __builtin_amdgcn_s_barrier();
  COMPUTE256(kt & 3)
#undef STAGE256
#undef COMPUTE256

  // epilogue: scale + bias + store (bf16 or fp32)
  const long cb = (long)blockIdx.z * sC;
#pragma unroll
  for (int ni = 0; ni < 4; ++ni) {
    const long col = bn + wn * 64 + ni * 16 + fr;
    const float bb = bias ? bias[col] : 0.f;
#pragma unroll
    for (int mi = 0; mi < 8; ++mi) {
      const long r0 = bm + wm * 128 + mi * 16 + ((lane >> 4) << 2);
#pragma unroll
      for (int r = 0; r < 4; ++r) {
        const float v = acc[mi][ni][r] * scale + bb;
        const long off = cb + (r0 + r) * (long)N + col;
        if (OBF) ((u16*)Cv)[off] = f2bf(v);
        else     ((float*)Cv)[off] = v;
      }
    }
  }
}

// ------------------------------ row softmax --------------------------------
__global__ __launch_bounds__(256) void k_softmax(const float* __restrict__ S,
                                                 u16* __restrict__ P) {
  __shared__ float red[8];
  const long row = blockIdx.x;
  const float* sr = S + (row << 10);
  const int t = threadIdx.x, lane = t & 63, w = t >> 6;
  float v0 = sr[t], v1 = sr[t + 256], v2 = sr[t + 512], v3 = sr[t + 768];
  float m = fmaxf(fmaxf(v0, v1), fmaxf(v2, v3));
#pragma unroll
  for (int o = 32; o; o >>= 1) m = fmaxf(m, __shfl_xor(m, o));
  if (lane == 0) red[w] = m;
  __syncthreads();
  m = fmaxf(fmaxf(red[0], red[1]), fmaxf(red[2], red[3]));
  v0 = __expf(v0 - m); v1 = __expf(v1 - m); v2 = __expf(v2 - m); v3 = __expf(v3 - m);
  float s = v0 + v1 + v2 + v3;
#pragma unroll
  for (int o = 32; o; o >>= 1) s += __shfl_xor(s, o);
  if (lane == 0) red[4 + w] = s;
  __syncthreads();
  s = red[4] + red[5] + red[6] + red[7];
  const float rs = 1.f / s;
  u16* pr = P + (row << 10);
  pr[t] = f2bf(v0 * rs); pr[t + 256] = f2bf(v1 * rs);
  pr[t + 512] = f2bf(v2 * rs); pr[t + 768] = f2bf(v3 * rs);
}

// ------------------------- V transpose (per batch) -------------------------
__global__ __launch_bounds__(256) void k_transpose(const u16* __restrict__ V,
                                                   u16* __restrict__ VT) {
  __shared__ __attribute__((aligned(16))) u16 tile[64][80];
  const long b = blockIdx.z;
  const long t0 = (long)blockIdx.y << 6, d0 = (long)blockIdx.x << 6;
  const int r = threadIdx.x >> 3, c8 = (threadIdx.x & 7) << 3;
  const u16* src = V + ((b << 10) + t0) * 2048 + d0;
#pragma unroll
  for (int p = 0; p < 2; ++p) {
    const int rr = r + p * 32;
    *(u16x8*)&tile[rr][c8] = *(const u16x8*)(src + (long)rr * 2048 + c8);
  }
  __syncthreads();
  u16* dst = VT + ((b << 11) + d0) * 1024 + t0;
#pragma unroll
  for (int p = 0; p < 2; ++p) {
    const int dr = r + p * 32;
    u16x8 pk;
#pragma unroll
    for (int q = 0; q < 8; ++q) pk[q] = tile[c8 + q][dr];
    *(u16x8*)(dst + (long)dr * 1024 + c8) = pk;
  }
}

// ------------------------------ LSTM recurrence ----------------------------
// ROUND-9 VERBATIM (best measured: ~5.1-5.2 ms).  128 blocks x 256 threads.
DEV bf16x8 wread(const char* wlds, int nrow, int k) {
  int byte = (nrow << 12) + (k << 1);
  byte ^= (nrow & 7) << 4;
  return *(const bf16x8*)(wlds + byte);
}
DEV float sigm(float x) { return 1.f / (1.f + __expf(-x)); }
DEV float tanh_fast(float x) { return 1.f - 2.f / (1.f + __expf(2.f * x)); }

__global__ __launch_bounds__(256, 1) void k_lstm(
    const u16* __restrict__ xg, const u16* __restrict__ whh,
    u16* __restrict__ hbuf, float* __restrict__ out,
    unsigned* __restrict__ flg) {
  extern __shared__ char smem[];
  char* wlds = smem;                       // 32 x 2048 bf16 = 131072 B (gates 0,1)
  float* red = (float*)(smem + 131072);    // [4 waves][16 batch x 64 gcol] = 16 KB
  const int tid = threadIdx.x, lane = tid & 63, wave = tid >> 6;
  const int j0 = blockIdx.x << 4;          // 16 columns per block
  const int am = lane & 15, ak = (lane >> 4) << 3;
  const int bb = tid >> 4, jj = tid & 15;  // gate-stage cell (all 256 threads)

  for (int it = 0; it < 32; ++it) {
    const long grow = ((long)(it >> 4) << 11) + j0 + (it & 15);
    const u16* src = whh + grow * 2048 + (tid << 3);
    int byte = (it << 12) + (tid << 4);
    byte ^= (it & 7) << 4;
    *(bf16x8*)(wlds + byte) = *(const bf16x8*)src;
  }
  bf16x8 wf[2][16];
#pragma unroll
  for (int g2 = 0; g2 < 2; ++g2)
#pragma unroll
    for (int ks = 0; ks < 16; ++ks)
      wf[g2][ks] = *(const bf16x8*)(whh + ((long)((2 + g2) << 11) + j0 + am) * 2048 +
                                    (wave << 9) + (ks << 5) + ak);
  __syncthreads();

  float c = 0.f;
  unsigned* const myflag = flg + (((wave << 5) + (lane & 31)) << 2);  // 16B stride
  u16 xv[4];
#pragma unroll
  for (int g = 0; g < 4; ++g)
    xv[g] = xg[((long)bb << 10) * 8192 + (g << 11) + j0 + jj];

  for (int t = 0; t < 1024; ++t) {
    const int par = t & 1;
    unsigned dep = 0;
    if (t) {
      const unsigned tgt = (unsigned)t;
      unsigned v = tgt;
      for (;;) {
        if (lane < 32)
          v = __hip_atomic_load(myflag, __ATOMIC_RELAXED, __HIP_MEMORY_SCOPE_AGENT);
        if (__all(v >= tgt)) break;
        __builtin_amdgcn_s_sleep(1);
      }
      dep = v >> 20;
    }
    asm volatile("" : "+v"(dep)::);

    const u16* hbase = hbuf + ((par ^ 1) << 15);
    const u32 voff = ((am << 11) + (wave << 9) + ak + dep) << 1;
    u32x4 hd[16];
#define HLD(I, OFF)                                                          \
    asm volatile("global_load_dwordx4 %0, %1, %2 offset:" #OFF " sc0 sc1"    \
                 : "=v"(hd[I]) : "v"(voff), "s"(hbase));
    HLD(0, 0)    HLD(1, 64)   HLD(2, 128)  HLD(3, 192)
    HLD(4, 256)  HLD(5, 320)  HLD(6, 384)  HLD(7, 448)
    HLD(8, 512)  HLD(9, 576)  HLD(10, 640) HLD(11, 704)
    HLD(12, 768) HLD(13, 832) HLD(14, 896) HLD(15, 960)
#undef HLD
    asm volatile("s_waitcnt vmcnt(0)" ::: "memory");
    __builtin_amdgcn_sched_barrier(0);

    f32x4 a0 = {0.f, 0.f, 0.f, 0.f}, a1 = a0, a2 = a0, a3 = a0;
#pragma unroll
    for (int ks = 0; ks < 16; ++ks) {
      union { u32x4 d; bf16x8 v; } u;
      u.d = hd[ks];
      const int k = (wave << 9) + (ks << 5) + ak;
      a0 = __builtin_amdgcn_mfma_f32_16x16x32_bf16(u.v, wread(wlds, am, k),      a0, 0, 0, 0);
      a1 = __builtin_amdgcn_mfma_f32_16x16x32_bf16(u.v, wread(wlds, am + 16, k), a1, 0, 0, 0);
      a2 = __builtin_amdgcn_mfma_f32_16x16x32_bf16(u.v, wf[0][ks], a2, 0, 0, 0);
      a3 = __builtin_amdgcn_mfma_f32_16x16x32_bf16(u.v, wf[1][ks], a3, 0, 0, 0);
    }
    {
      float* rw = red + (wave << 10);
      const int mrow = (lane >> 4) << 2;
#pragma unroll
      for (int r = 0; r < 4; ++r) {
        rw[(mrow + r) * 64 + am]      = a0[r];
        rw[(mrow + r) * 64 + 16 + am] = a1[r];
        rw[(mrow + r) * 64 + 32 + am] = a2[r];
        rw[(mrow + r) * 64 + 48 + am] = a3[r];
      }
    }
    __syncthreads();
    float g4[4];
#pragma unroll
    for (int g = 0; g < 4; ++g) {
      const int n = (bb << 6) + (g << 4) + jj;
      g4[g] = red[n] + red[1024 + n] + red[2048 + n] + red[3072 + n] + bf2f(xv[g]);
    }
    const float gi = sigm(g4[0]);
    const float gf = sigm(g4[1]);
    const float gg = tanh_fast(g4[2]);
    const float go = sigm(g4[3]);
    c = gf * c + gi * gg;
    const float h = go * tanh_fast(c);
    {
      const unsigned hb = (unsigned)f2bf(h);
      const unsigned p1 = (unsigned)__shfl_xor((int)hb, 1);
      const unsigned w2 = (hb & 0xFFFFu) | (p1 << 16);
      const unsigned p2 = (unsigned)__shfl_xor((int)w2, 2);
      if ((jj & 3) == 0) {
        const u64 hw = (u64)w2 | ((u64)p2 << 32);
        u16* dst = hbuf + (par << 15) + (bb << 11) + j0 + jj;
        __hip_atomic_store((u64*)dst, hw, __ATOMIC_RELAXED, __HIP_MEMORY_SCOPE_AGENT);
      }
    }
    asm volatile("s_waitcnt vmcnt(0)" ::: "memory");
    __syncthreads();
    if (tid == 0)
      __hip_atomic_store(flg + (blockIdx.x << 2), (unsigned)(t + 1),
                         __ATOMIC_RELAXED, __HIP_MEMORY_SCOPE_AGENT);
    out[(((long)(bb << 10) + t) << 11) + j0 + jj] = h;
    {
      const int tn = (t + 1 < 1024) ? t + 1 : 0;
#pragma unroll
      for (int g = 0; g < 4; ++g)
        xv[g] = xg[((long)((bb << 10) + tn)) * 8192 + (g << 11) + j0 + jj];
    }
    asm volatile("" ::: "memory");
  }
}

// ------------------------------- launcher ----------------------------------
extern "C" void kernel_launch(void* const* d_in, const int* in_sizes, int n_in,
                              void* d_out, int out_size, void* d_ws, size_t ws_size,
                              hipStream_t stream) {
  const float* feats = (const float*)d_in[0];
  const float* Wq = (const float*)d_in[1];
  const float* bq = (const float*)d_in[2];
  const float* Wk = (const float*)d_in[3];
  const float* bk = (const float*)d_in[4];
  const float* Wv = (const float*)d_in[5];
  const float* bv = (const float*)d_in[6];
  const float* Wih = (const float*)d_in[7];
  const float* Whh = (const float*)d_in[8];
  const float* bih = (const float*)d_in[9];
  const float* bhh = (const float*)d_in[10];
  float* out = (float*)d_out;
  char* ws = (char*)d_ws;

  u16* feats16 = (u16*)(ws + 0L);
  u16* q16     = (u16*)(ws + 67108864L);   // q,k,v uniform 64MB stride
  u16* k16     = (u16*)(ws + 134217728L);
  u16* v16     = (u16*)(ws + 201326592L);
  u16* vT16    = feats16;                   // reuse after QKV
  u16* P16     = q16;                       // reuse after scores GEMM
  u16* xg16    = (u16*)(ws + 0L);           // reuse [0,256MB) after PV
  u16* nf16    = (u16*)(ws + 268435456L);
  u16* wq16    = (u16*)(ws + 335544320L);  // wq,wk,wv contiguous (8MB apart)
  u16* wk16    = (u16*)(ws + 343932928L);
  u16* wv16    = (u16*)(ws + 352321536L);
  u16* wih16   = (u16*)(ws + 360710144L);
  u16* whh16   = (u16*)(ws + 394264576L);
  float* biassum = (float*)(ws + 427819008L);
  u16* hbuf    = (u16*)(ws + 427851776L);   // [2][16][2048] bf16
  unsigned* flg = (unsigned*)(ws + 427982848L);  // 128 x 16B flag slots
  float* biasqkv = (float*)(ws + 427999232L);    // [3][2048] f32
  float* scoresf = (float*)d_out;           // d_out as scratch; LSTM overwrites

  // conversions + bias prep (2 dispatches instead of 7)
  k_cvt6<<<38912, 256, 0, stream>>>(feats, feats16, Wq, wq16, Wk, wk16,
                                    Wv, wv16, Wih, wih16, Whh, whh16);
  k_biasprep<<<56, 256, 0, stream>>>(bq, bk, bv, bih, bhh, biasqkv, biassum);

  (void)hipFuncSetAttribute((const void*)k_gemm256<1>, hipFuncAttributeMaxDynamicSharedMemorySize, 131072);
  (void)hipFuncSetAttribute((const void*)k_gemm256<0>, hipFuncAttributeMaxDynamicSharedMemorySize, 131072);
  // q,k,v = feats @ W^T + b   (ONE batched dispatch, z = weight index)
  k_gemm256<1><<<dim3(8, 64, 3), 512, 131072, stream>>>(
      feats16, wq16, q16, biasqkv, 1.f, 2048, 2048,
      0, 4194304, 33554432, 2048);
  // scores = q k^T / sqrt(2048)   (batched 256², fp32 into d_out scratch)
  k_gemm256<0><<<dim3(4, 4, 16), 512, 131072, stream>>>(
      q16, k16, scoresf, nullptr, 0.022097086912079608f, 1024, 2048,
      2097152, 2097152, 1048576, 0);
  k_softmax<<<16384, 256, 0, stream>>>(scoresf, P16);
  k_transpose<<<dim3(32, 16, 16), 256, 0, stream>>>(v16, vT16);
  // new_feats = P @ V  (via V^T, batched 256²)
  k_gemm256<1><<<dim3(8, 4, 16), 512, 131072, stream>>>(
      P16, vT16, nf16, nullptr, 1.f, 2048, 1024,
      1048576, 2097152, 2097152, 0);
  // xg = new_feats @ W_ih^T + (b_ih + b_hh)
  k_gemm256<1><<<dim3(32, 64, 1), 512, 131072, stream>>>(
      nf16, wih16, xg16, biassum, 1.f, 8192, 2048, 0, 0, 0, 0);

  // LSTM recurrence (persistent kernel, R9 per-wave flag sync)
  hipMemsetAsync(ws + 427851776L, 0, 131072 + 4096, stream);  // hbuf + flags
  const int dynlds = 131072 + 16384;  // W gates 0,1 + red
  (void)hipFuncSetAttribute((const void*)k_lstm, hipFuncAttributeMaxDynamicSharedMemorySize, dynlds);
  void* kargs[] = {(void*)&xg16, (void*)&whh16, (void*)&hbuf, (void*)&out, (void*)&flg};
  hipError_t ce = hipLaunchCooperativeKernel((const void*)k_lstm, dim3(128), dim3(256),
                                             kargs, dynlds, stream);
  if (ce != hipSuccess) {
    k_lstm<<<dim3(128), dim3(256), dynlds, stream>>>(xg16, whh16, hbuf, out, flg);
  }
}